// Round 6
// baseline (417.520 us; speedup 1.0000x reference)
//
#include <hip/hip_runtime.h>
#include <math.h>

#define S_LEN 2048
#define B_SZ 2
#define NHEAD 16
#define HDIM 64
#define H_DIM 1024
#define M_ROWS (S_LEN * B_SZ)   // 4096
#define LN_EPS 1e-5f
#define KSTR 72                  // attn LDS row stride (shorts): 2-way banks = free
#define SCL 0.18033688011112042f // 0.125 * log2(e)

typedef __attribute__((ext_vector_type(4))) float f32x4;
typedef __attribute__((ext_vector_type(8))) short short8;
typedef __attribute__((ext_vector_type(8))) unsigned short u16x8;
typedef __attribute__((ext_vector_type(4))) unsigned short u16x4;
typedef __attribute__((ext_vector_type(2))) unsigned short u16x2;

__device__ __forceinline__ float bf2f(unsigned short u) {
    return __uint_as_float(((unsigned int)u) << 16);
}
__device__ __forceinline__ unsigned short f2bf(float f) {
    unsigned int u = __float_as_uint(f);
    return (unsigned short)((u + 0x7fffu + ((u >> 16) & 1u)) >> 16);
}
__device__ __forceinline__ void gld_lds16(const void* g, void* l) {
    __builtin_amdgcn_global_load_lds(
        (const __attribute__((address_space(1))) void*)g,
        (__attribute__((address_space(3))) void*)l, 16, 0, 0);
}

// ---------------- weight cast fp32 -> bf16 ----------------------------------
__global__ __launch_bounds__(256) void cast_w(const float* __restrict__ in,
                                              unsigned short* __restrict__ out,
                                              int n4) {
    const int i = blockIdx.x * 256 + threadIdx.x;
    if (i < n4) {
        f32x4 v = ((const f32x4*)in)[i];
        u16x4 o;
        o.x = f2bf(v.x); o.y = f2bf(v.y); o.z = f2bf(v.z); o.w = f2bf(v.w);
        ((u16x4*)out)[i] = o;
    }
}

// ---------------- LayerNorm row of 1024 -> bf16 -----------------------------
__global__ __launch_bounds__(256) void ln_bf16(const float* __restrict__ x,
                                               const float* __restrict__ w,
                                               const float* __restrict__ b,
                                               unsigned short* __restrict__ y) {
    const int m = blockIdx.x;
    const int tid = threadIdx.x;
    const float* row = x + (size_t)m * H_DIM;

    float4 v = ((const float4*)row)[tid];
    float s  = v.x + v.y + v.z + v.w;
    float ss = v.x * v.x + v.y * v.y + v.z * v.z + v.w * v.w;

    __shared__ float rs[4], rss[4], stats[2];
    const int wave = tid >> 6, lane = tid & 63;
    for (int off = 32; off; off >>= 1) {
        s  += __shfl_down(s, off);
        ss += __shfl_down(ss, off);
    }
    if (lane == 0) { rs[wave] = s; rss[wave] = ss; }
    __syncthreads();
    if (tid == 0) {
        float S = rs[0] + rs[1] + rs[2] + rs[3];
        float SS = rss[0] + rss[1] + rss[2] + rss[3];
        float mean = S * (1.0f / H_DIM);
        float var = SS * (1.0f / H_DIM) - mean * mean;
        stats[0] = mean;
        stats[1] = rsqrtf(var + LN_EPS);
    }
    __syncthreads();
    const float mean = stats[0], inv = stats[1];
    float4 wv = ((const float4*)w)[tid];
    float4 bv = ((const float4*)b)[tid];
    u16x4 o;
    o.x = f2bf((v.x - mean) * inv * wv.x + bv.x);
    o.y = f2bf((v.y - mean) * inv * wv.y + bv.y);
    o.z = f2bf((v.z - mean) * inv * wv.z + bv.z);
    o.w = f2bf((v.w - mean) * inv * wv.w + bv.w);
    ((u16x4*)(y + (size_t)m * H_DIM))[tid] = o;
}

// ---------------- bf16 MFMA GEMM, dbuf + XCD swizzle + coalesced epi --------
// C[M,N] = A[M,K] @ B[N,K]^T + bias. EPI: 0=bias, 1=+resid, 2=+gelu. 1D grid.
// MFMA operand order (B-frag first) => per-lane acc regs are 4 CONSECUTIVE n
// at fixed m: vectorized u16x4/f32x4 stores, line-merged across the j loop.
template <int EPI, bool BF_OUT>
__global__ __launch_bounds__(256) void gemm_mfma(const unsigned short* __restrict__ A,
                                                 const unsigned short* __restrict__ B,
                                                 const float* __restrict__ bias,
                                                 const float* __restrict__ resid,
                                                 void* __restrict__ Cout,
                                                 int M, int N, int K) {
    __shared__ __attribute__((aligned(16))) unsigned short As[2][128 * 32];
    __shared__ __attribute__((aligned(16))) unsigned short Bs[2][128 * 32];

    const int tid = threadIdx.x;
    const int wid = tid >> 6;
    const int ln  = tid & 63;
    const int quad = ln >> 4;
    const int mr   = ln & 15;
    const int wm = (wid >> 1) * 64;
    const int wn = (wid & 1) * 64;

    const int mb = M >> 7;
    const int stripe = mb >> 3;               // 4 for M=4096
    const int xcd = blockIdx.x & 7;
    const int local = blockIdx.x >> 3;
    const int m0 = (xcd * stripe + (local % stripe)) << 7;
    const int n0 = (local / stripe) << 7;

    const int c  = wid * 64 + ln;
    const int r0 = c >> 2;
    const int k0 = (c & 3) * 8;
    const unsigned short* gA0 = A + (size_t)(m0 + r0) * K + k0;
    const unsigned short* gA1 = A + (size_t)(m0 + 64 + r0) * K + k0;
    const unsigned short* gB0 = B + (size_t)(n0 + r0) * K + k0;
    const unsigned short* gB1 = B + (size_t)(n0 + 64 + r0) * K + k0;
    const int lo0 = wid * 512;
    const int lo1 = 2048 + wid * 512;

    const f32x4 zero = {0.f, 0.f, 0.f, 0.f};
    f32x4 acc[4][4];
#pragma unroll
    for (int i = 0; i < 4; i++)
#pragma unroll
        for (int j = 0; j < 4; j++) acc[i][j] = zero;

    const int nt = K >> 5;
    gld_lds16(gA0, As[0] + lo0);
    gld_lds16(gA1, As[0] + lo1);
    gld_lds16(gB0, Bs[0] + lo0);
    gld_lds16(gB1, Bs[0] + lo1);

    for (int kt = 0; kt < nt; kt++) {
        __syncthreads();
        const int nxt = kt + 1;
        if (nxt < nt) {
            const int nb_ = nxt & 1;
            const int koff = nxt * 32;
            gld_lds16(gA0 + koff, As[nb_] + lo0);
            gld_lds16(gA1 + koff, As[nb_] + lo1);
            gld_lds16(gB0 + koff, Bs[nb_] + lo0);
            gld_lds16(gB1 + koff, Bs[nb_] + lo1);
        }
        const unsigned short* as = As[kt & 1];
        const unsigned short* bs = Bs[kt & 1];
        short8 af[4], bfr[4];
#pragma unroll
        for (int i = 0; i < 4; i++)
            af[i] = *(const short8*)(as + (wm + i * 16 + mr) * 32 + quad * 8);
#pragma unroll
        for (int j = 0; j < 4; j++)
            bfr[j] = *(const short8*)(bs + (wn + j * 16 + mr) * 32 + quad * 8);
#pragma unroll
        for (int i = 0; i < 4; i++)
#pragma unroll
            for (int j = 0; j < 4; j++)
                acc[i][j] = __builtin_amdgcn_mfma_f32_16x16x32_bf16(bfr[j], af[i], acc[i][j], 0, 0, 0);
    }

    // epilogue: per-lane 4 consecutive n at fixed m; j-inner stores merge lines
    f32x4 bias4[4];
#pragma unroll
    for (int j = 0; j < 4; j++)
        bias4[j] = *(const f32x4*)(bias + n0 + wn + j * 16 + quad * 4);

#pragma unroll
    for (int i = 0; i < 4; i++) {
        const int m = m0 + wm + i * 16 + mr;
#pragma unroll
        for (int j = 0; j < 4; j++) {
            const int nb = n0 + wn + j * 16 + quad * 4;
            f32x4 v = acc[i][j] + bias4[j];
            if (EPI == 1) v += *(const f32x4*)(resid + (size_t)m * N + nb);
            if (EPI == 2) {
#pragma unroll
                for (int r = 0; r < 4; r++) {
                    const float t = v[r];
                    v[r] = 0.5f * t * (1.0f + tanhf(0.7978845608f * (t + 0.044715f * t * t * t)));
                }
            }
            if (BF_OUT) {
                u16x4 pk;
                pk.x = f2bf(v.x); pk.y = f2bf(v.y); pk.z = f2bf(v.z); pk.w = f2bf(v.w);
                *(u16x4*)((unsigned short*)Cout + (size_t)m * N + nb) = pk;
            } else {
                *(f32x4*)((float*)Cout + (size_t)m * N + nb) = v;
            }
        }
    }
}

// ---------------- MFMA flash attention, XCD-local + reg-prefetch ------------
__global__ __launch_bounds__(256) void attn_mfma(const unsigned short* __restrict__ qkv,
                                                 unsigned short* __restrict__ out) {
    __shared__ __attribute__((aligned(16))) unsigned short Ks[64 * KSTR];
    __shared__ __attribute__((aligned(16))) unsigned short Vs[64 * KSTR];
    __shared__ __attribute__((aligned(16))) unsigned short Ps[64 * KSTR];

    const int tid = threadIdx.x;
    const int wid = tid >> 6;
    const int ln  = tid & 63;
    const int quad = ln >> 4;
    const int mr   = ln & 15;

    const int id = blockIdx.x;                 // 0..511
    const int local = id >> 3;                 // 0..63
    const int bh = (id & 7) * 4 + (local >> 4);
    const int pa = local & 15;
    const int b  = bh >> 4;
    const int nh = bh & 15;
    const size_t chan = (size_t)nh * 192;

    const int ksr = tid >> 2, ksc = tid & 3;
    const int vt0 = (tid & 31) * 2, vd0 = (tid >> 5) * 8;

    u16x8 kp0, kp1, vp0, vp1;   // prefetch registers

#pragma unroll
    for (int half = 0; half < 2; half++) {
        const int qt = half ? (31 - pa) : pa;
        const int qb = qt * 64;

        short8 qf0, qf1;
        {
            const int qrow = qb + wid * 16 + mr;
            const unsigned short* gq = qkv + ((size_t)(qrow * 2 + b)) * 3072 + chan + quad * 8;
            qf0 = *(const short8*)gq;
            qf1 = *(const short8*)(gq + 32);
        }

        const f32x4 zero = {0.f, 0.f, 0.f, 0.f};
        f32x4 o[4];
        float mo[4], lo[4];
#pragma unroll
        for (int d = 0; d < 4; d++) o[d] = zero;
#pragma unroll
        for (int r = 0; r < 4; r++) { mo[r] = -3.0e38f; lo[r] = 0.f; }

        {
            const unsigned short* gk = qkv + ((size_t)(ksr * 2 + b)) * 3072 + chan + 64 + ksc * 16;
            kp0 = *(const u16x8*)gk;
            kp1 = *(const u16x8*)(gk + 8);
            const unsigned short* gv = qkv + ((size_t)(vt0 * 2 + b)) * 3072 + chan + 128 + vd0;
            vp0 = *(const u16x8*)gv;
            vp1 = *(const u16x8*)(gv + 6144);
        }

        for (int kt = 0; kt <= qt; kt++) {
            __syncthreads();
            *(u16x8*)(Ks + ksr * KSTR + ksc * 16) = kp0;
            *(u16x8*)(Ks + ksr * KSTR + ksc * 16 + 8) = kp1;
#pragma unroll
            for (int j = 0; j < 8; j++) {
                u16x2 pr; pr.x = vp0[j]; pr.y = vp1[j];
                *(u16x2*)(Vs + (vd0 + j) * KSTR + vt0) = pr;
            }
            if (kt < qt) {
                const int nb = (kt + 1) * 64;
                const unsigned short* gk =
                    qkv + ((size_t)((nb + ksr) * 2 + b)) * 3072 + chan + 64 + ksc * 16;
                kp0 = *(const u16x8*)gk;
                kp1 = *(const u16x8*)(gk + 8);
                const unsigned short* gv =
                    qkv + ((size_t)((nb + vt0) * 2 + b)) * 3072 + chan + 128 + vd0;
                vp0 = *(const u16x8*)gv;
                vp1 = *(const u16x8*)(gv + 6144);
            }
            __syncthreads();

            f32x4 sacc[4];
#pragma unroll
            for (int n = 0; n < 4; n++) {
                sacc[n] = zero;
                const unsigned short* kb = Ks + (n * 16 + mr) * KSTR + quad * 8;
                short8 kfr0 = *(const short8*)kb;
                short8 kfr1 = *(const short8*)(kb + 32);
                sacc[n] = __builtin_amdgcn_mfma_f32_16x16x32_bf16(qf0, kfr0, sacc[n], 0, 0, 0);
                sacc[n] = __builtin_amdgcn_mfma_f32_16x16x32_bf16(qf1, kfr1, sacc[n], 0, 0, 0);
            }
            if (kt == qt) {
#pragma unroll
                for (int n = 0; n < 4; n++)
#pragma unroll
                    for (int r = 0; r < 4; r++)
                        if (n * 16 + mr > wid * 16 + quad * 4 + r) sacc[n][r] = -3.0e38f;
            }

#pragma unroll
            for (int r = 0; r < 4; r++) {
                float rm = fmaxf(fmaxf(sacc[0][r], sacc[1][r]), fmaxf(sacc[2][r], sacc[3][r]));
                rm = fmaxf(rm, __shfl_xor(rm, 1));
                rm = fmaxf(rm, __shfl_xor(rm, 2));
                rm = fmaxf(rm, __shfl_xor(rm, 4));
                rm = fmaxf(rm, __shfl_xor(rm, 8));
                const float mn = fmaxf(mo[r], rm);
                const float al = exp2f((mo[r] - mn) * SCL);
                mo[r] = mn;
                const float off = -mn * SCL;
                float ps = 0.f;
                unsigned short* prow = Ps + (wid * 16 + quad * 4 + r) * KSTR + mr;
#pragma unroll
                for (int n = 0; n < 4; n++) {
                    const float p = exp2f(fmaf(sacc[n][r], SCL, off));
                    const unsigned short pb = (unsigned short)(__float_as_uint(p) >> 16);
                    prow[n * 16] = pb;
                    ps += bf2f(pb);
                }
                lo[r] = lo[r] * al + ps;
#pragma unroll
                for (int d = 0; d < 4; d++) o[d][r] *= al;
            }

            {
                const unsigned short* pb = Ps + (wid * 16 + mr) * KSTR + quad * 8;
                short8 pa0 = *(const short8*)pb;
                short8 pa1 = *(const short8*)(pb + 32);
#pragma unroll
                for (int d = 0; d < 4; d++) {
                    const unsigned short* vb = Vs + (d * 16 + mr) * KSTR + quad * 8;
                    short8 vf0 = *(const short8*)vb;
                    short8 vf1 = *(const short8*)(vb + 32);
                    o[d] = __builtin_amdgcn_mfma_f32_16x16x32_bf16(pa0, vf0, o[d], 0, 0, 0);
                    o[d] = __builtin_amdgcn_mfma_f32_16x16x32_bf16(pa1, vf1, o[d], 0, 0, 0);
                }
            }
        }

#pragma unroll
        for (int r = 0; r < 4; r++) {
            float ls = lo[r];
            ls += __shfl_xor(ls, 1);
            ls += __shfl_xor(ls, 2);
            ls += __shfl_xor(ls, 4);
            ls += __shfl_xor(ls, 8);
            const float inv = 1.0f / ls;
            const int qrow = qb + wid * 16 + quad * 4 + r;
            unsigned short* po = out + ((size_t)(qrow * 2 + b)) * H_DIM + nh * HDIM + mr;
#pragma unroll
            for (int d = 0; d < 4; d++) po[d * 16] = f2bf(o[d][r] * inv);
        }
    }
}

extern "C" void kernel_launch(void* const* d_in, const int* in_sizes, int n_in,
                              void* d_out, int out_size, void* d_ws, size_t ws_size,
                              hipStream_t stream) {
    const float* x      = (const float*)d_in[0];
    const float* ln1_w  = (const float*)d_in[1];
    const float* ln1_b  = (const float*)d_in[2];
    const float* w_qkv  = (const float*)d_in[3];
    const float* b_qkv  = (const float*)d_in[4];
    const float* w_proj = (const float*)d_in[5];
    const float* b_proj = (const float*)d_in[6];
    const float* ln2_w  = (const float*)d_in[7];
    const float* ln2_b  = (const float*)d_in[8];
    const float* w_fc1  = (const float*)d_in[9];
    const float* b_fc1  = (const float*)d_in[10];
    const float* w_fc2  = (const float*)d_in[11];
    const float* b_fc2  = (const float*)d_in[12];
    float* out = (float*)d_out;

    char* ws = (char*)d_ws;
    unsigned short* wqkv_bf  = (unsigned short*)(ws);                        // 6 MB
    unsigned short* wproj_bf = (unsigned short*)(ws + ((size_t)6 << 20));    // 2 MB
    unsigned short* wfc1_bf  = (unsigned short*)(ws + ((size_t)8 << 20));    // 8 MB
    unsigned short* wfc2_bf  = (unsigned short*)(ws + ((size_t)16 << 20));   // 8 MB
    unsigned short* ln_buf   = (unsigned short*)(ws + ((size_t)24 << 20));   // 8 MB
    unsigned short* qkv_bf   = (unsigned short*)(ws + ((size_t)32 << 20));   // 24 MB
    unsigned short* attn_bf  = (unsigned short*)(ws + ((size_t)56 << 20));   // 8 MB
    unsigned short* fc1_bf   = (unsigned short*)(ws + ((size_t)32 << 20));   // 32 MB (qkv/attn dead)

    cast_w<<<3072, 256, 0, stream>>>(w_qkv,  wqkv_bf,  3 * 1024 * 1024 / 4);
    cast_w<<<1024, 256, 0, stream>>>(w_proj, wproj_bf, 1024 * 1024 / 4);
    cast_w<<<4096, 256, 0, stream>>>(w_fc1,  wfc1_bf,  4 * 1024 * 1024 / 4);
    cast_w<<<4096, 256, 0, stream>>>(w_fc2,  wfc2_bf,  4 * 1024 * 1024 / 4);

    // 1) LN1 -> bf16
    ln_bf16<<<M_ROWS, 256, 0, stream>>>(x, ln1_w, ln1_b, ln_buf);
    // 2) qkv = ln1 @ w_qkv^T + b_qkv   [4096,3072] bf16   (768 blocks)
    gemm_mfma<0, true><<<768, 256, 0, stream>>>(
        ln_buf, wqkv_bf, b_qkv, nullptr, qkv_bf, M_ROWS, 3072, 1024);
    // 3) MFMA flash attention -> bf16 [4096,1024]   (512 blocks, XCD-local)
    attn_mfma<<<512, 256, 0, stream>>>(qkv_bf, attn_bf);
    // 4) x1 = x + attn @ w_proj^T + b_proj  -> d_out (fp32)   (256 blocks)
    gemm_mfma<1, false><<<256, 256, 0, stream>>>(
        attn_bf, wproj_bf, b_proj, x, out, M_ROWS, 1024, 1024);
    // 5) LN2 -> bf16
    ln_bf16<<<M_ROWS, 256, 0, stream>>>(out, ln2_w, ln2_b, ln_buf);
    // 6) fc1 + gelu -> bf16 [4096,4096]   (1024 blocks)
    gemm_mfma<2, true><<<1024, 256, 0, stream>>>(
        ln_buf, wfc1_bf, b_fc1, nullptr, fc1_bf, M_ROWS, 4096, 1024);
    // 7) out = x1 + fc1 @ w_fc2^T + b_fc2 (in-place residual)   (256 blocks)
    gemm_mfma<1, false><<<256, 256, 0, stream>>>(
        fc1_bf, wfc2_bf, b_fc2, out, out, M_ROWS, 1024, 4096);
}

// Round 7
// 395.276 us; speedup vs baseline: 1.0563x; 1.0563x over previous
//
#include <hip/hip_runtime.h>
#include <math.h>

#define S_LEN 2048
#define B_SZ 2
#define NHEAD 16
#define HDIM 64
#define H_DIM 1024
#define M_ROWS (S_LEN * B_SZ)   // 4096
#define LN_EPS 1e-5f
#define KSTR 72                  // attn LDS row stride (shorts): 2-way banks = free
#define SCL 0.18033688011112042f // 0.125 * log2(e)

typedef __attribute__((ext_vector_type(4))) float f32x4;
typedef __attribute__((ext_vector_type(8))) short short8;
typedef __attribute__((ext_vector_type(8))) unsigned short u16x8;
typedef __attribute__((ext_vector_type(4))) unsigned short u16x4;
typedef __attribute__((ext_vector_type(2))) unsigned short u16x2;

__device__ __forceinline__ float bf2f(unsigned short u) {
    return __uint_as_float(((unsigned int)u) << 16);
}
__device__ __forceinline__ unsigned short f2bf(float f) {
    unsigned int u = __float_as_uint(f);
    return (unsigned short)((u + 0x7fffu + ((u >> 16) & 1u)) >> 16);
}
__device__ __forceinline__ void gld_lds16(const void* g, void* l) {
    __builtin_amdgcn_global_load_lds(
        (const __attribute__((address_space(1))) void*)g,
        (__attribute__((address_space(3))) void*)l, 16, 0, 0);
}

// ---------------- fused weight cast fp32 -> bf16 (single launch) ------------
// segments (f32x4 units): qkv 786432 | proj 262144 | fc1 1048576 | fc2 1048576
__global__ __launch_bounds__(256) void cast_all(const float* __restrict__ wqkv,
                                                const float* __restrict__ wproj,
                                                const float* __restrict__ wfc1,
                                                const float* __restrict__ wfc2,
                                                unsigned short* __restrict__ oqkv,
                                                unsigned short* __restrict__ oproj,
                                                unsigned short* __restrict__ ofc1,
                                                unsigned short* __restrict__ ofc2) {
    const int i = blockIdx.x * 256 + threadIdx.x;   // grid covers 3145728
    const float* src; unsigned short* dst; int off;
    if (i < 786432)       { src = wqkv;  dst = oqkv;  off = i; }
    else if (i < 1048576) { src = wproj; dst = oproj; off = i - 786432; }
    else if (i < 2097152) { src = wfc1;  dst = ofc1;  off = i - 1048576; }
    else                  { src = wfc2;  dst = ofc2;  off = i - 2097152; }
    f32x4 v = ((const f32x4*)src)[off];
    u16x4 o;
    o.x = f2bf(v.x); o.y = f2bf(v.y); o.z = f2bf(v.z); o.w = f2bf(v.w);
    ((u16x4*)dst)[off] = o;
}

// ---------------- LayerNorm row of 1024 -> bf16 -----------------------------
__global__ __launch_bounds__(256) void ln_bf16(const float* __restrict__ x,
                                               const float* __restrict__ w,
                                               const float* __restrict__ b,
                                               unsigned short* __restrict__ y) {
    const int m = blockIdx.x;
    const int tid = threadIdx.x;
    const float* row = x + (size_t)m * H_DIM;

    float4 v = ((const float4*)row)[tid];
    float s  = v.x + v.y + v.z + v.w;
    float ss = v.x * v.x + v.y * v.y + v.z * v.z + v.w * v.w;

    __shared__ float rs[4], rss[4], stats[2];
    const int wave = tid >> 6, lane = tid & 63;
    for (int off = 32; off; off >>= 1) {
        s  += __shfl_down(s, off);
        ss += __shfl_down(ss, off);
    }
    if (lane == 0) { rs[wave] = s; rss[wave] = ss; }
    __syncthreads();
    if (tid == 0) {
        float S = rs[0] + rs[1] + rs[2] + rs[3];
        float SS = rss[0] + rss[1] + rss[2] + rss[3];
        float mean = S * (1.0f / H_DIM);
        float var = SS * (1.0f / H_DIM) - mean * mean;
        stats[0] = mean;
        stats[1] = rsqrtf(var + LN_EPS);
    }
    __syncthreads();
    const float mean = stats[0], inv = stats[1];
    float4 wv = ((const float4*)w)[tid];
    float4 bv = ((const float4*)b)[tid];
    u16x4 o;
    o.x = f2bf((v.x - mean) * inv * wv.x + bv.x);
    o.y = f2bf((v.y - mean) * inv * wv.y + bv.y);
    o.z = f2bf((v.z - mean) * inv * wv.z + bv.z);
    o.w = f2bf((v.w - mean) * inv * wv.w + bv.w);
    ((u16x4*)(y + (size_t)m * H_DIM))[tid] = o;
}

// ---------------- bf16 MFMA GEMM, dbuf + XCD swizzle + coalesced epi --------
// C[M,N] = A[M,K] @ B[N,K]^T + bias. EPI: 0=bias, 1=+resid, 2=+gelu.
// TN = block n-tile (128 or 64). TN=64 doubles the grid for thin-N shapes
// (proj/fc2: 256 -> 512 blocks = 2 blocks/CU) to hide global latency.
template <int EPI, bool BF_OUT, int TN>
__global__ __launch_bounds__(256) void gemm_mfma(const unsigned short* __restrict__ A,
                                                 const unsigned short* __restrict__ B,
                                                 const float* __restrict__ bias,
                                                 const float* __restrict__ resid,
                                                 void* __restrict__ Cout,
                                                 int M, int N, int K) {
    constexpr int NJ = TN / 32;   // n-frags per wave
    __shared__ __attribute__((aligned(16))) unsigned short As[2][128 * 32];
    __shared__ __attribute__((aligned(16))) unsigned short Bs[2][TN * 32];

    const int tid = threadIdx.x;
    const int wid = tid >> 6;
    const int ln  = tid & 63;
    const int quad = ln >> 4;
    const int mr   = ln & 15;
    const int wm = (wid >> 1) * 64;
    const int wn = (wid & 1) * (TN / 2);

    const int mb = M >> 7;
    const int stripe = mb >> 3;               // 4 for M=4096
    const int xcd = blockIdx.x & 7;
    const int local = blockIdx.x >> 3;
    const int m0 = (xcd * stripe + (local % stripe)) << 7;
    const int n0 = (local / stripe) * TN;

    const int c  = wid * 64 + ln;
    const int r0 = c >> 2;
    const int k0 = (c & 3) * 8;
    const unsigned short* gA0 = A + (size_t)(m0 + r0) * K + k0;
    const unsigned short* gA1 = A + (size_t)(m0 + 64 + r0) * K + k0;
    const unsigned short* gB0 = B + (size_t)(n0 + r0) * K + k0;
    const unsigned short* gB1 = B + (size_t)(n0 + 64 + r0) * K + k0;  // TN=128 only
    const int lo0 = wid * 512;
    const int lo1 = 2048 + wid * 512;

    const f32x4 zero = {0.f, 0.f, 0.f, 0.f};
    f32x4 acc[4][NJ];
#pragma unroll
    for (int i = 0; i < 4; i++)
#pragma unroll
        for (int j = 0; j < NJ; j++) acc[i][j] = zero;

    const int nt = K >> 5;
    gld_lds16(gA0, As[0] + lo0);
    gld_lds16(gA1, As[0] + lo1);
    gld_lds16(gB0, Bs[0] + lo0);
    if constexpr (TN == 128) gld_lds16(gB1, Bs[0] + lo1);

    for (int kt = 0; kt < nt; kt++) {
        __syncthreads();
        const int nxt = kt + 1;
        if (nxt < nt) {
            const int nb_ = nxt & 1;
            const int koff = nxt * 32;
            gld_lds16(gA0 + koff, As[nb_] + lo0);
            gld_lds16(gA1 + koff, As[nb_] + lo1);
            gld_lds16(gB0 + koff, Bs[nb_] + lo0);
            if constexpr (TN == 128) gld_lds16(gB1 + koff, Bs[nb_] + lo1);
        }
        const unsigned short* as = As[kt & 1];
        const unsigned short* bs = Bs[kt & 1];
        short8 af[4], bfr[NJ];
#pragma unroll
        for (int i = 0; i < 4; i++)
            af[i] = *(const short8*)(as + (wm + i * 16 + mr) * 32 + quad * 8);
#pragma unroll
        for (int j = 0; j < NJ; j++)
            bfr[j] = *(const short8*)(bs + (wn + j * 16 + mr) * 32 + quad * 8);
#pragma unroll
        for (int i = 0; i < 4; i++)
#pragma unroll
            for (int j = 0; j < NJ; j++)
                acc[i][j] = __builtin_amdgcn_mfma_f32_16x16x32_bf16(bfr[j], af[i], acc[i][j], 0, 0, 0);
    }

    // epilogue: per-lane 4 consecutive n at fixed m; j-inner stores merge lines
    f32x4 bias4[NJ];
#pragma unroll
    for (int j = 0; j < NJ; j++)
        bias4[j] = *(const f32x4*)(bias + n0 + wn + j * 16 + quad * 4);

#pragma unroll
    for (int i = 0; i < 4; i++) {
        const int m = m0 + wm + i * 16 + mr;
#pragma unroll
        for (int j = 0; j < NJ; j++) {
            const int nb = n0 + wn + j * 16 + quad * 4;
            f32x4 v = acc[i][j] + bias4[j];
            if (EPI == 1) v += *(const f32x4*)(resid + (size_t)m * N + nb);
            if (EPI == 2) {
#pragma unroll
                for (int r = 0; r < 4; r++) {
                    const float t = v[r];
                    v[r] = 0.5f * t * (1.0f + tanhf(0.7978845608f * (t + 0.044715f * t * t * t)));
                }
            }
            if (BF_OUT) {
                u16x4 pk;
                pk.x = f2bf(v.x); pk.y = f2bf(v.y); pk.z = f2bf(v.z); pk.w = f2bf(v.w);
                *(u16x4*)((unsigned short*)Cout + (size_t)m * N + nb) = pk;
            } else {
                *(f32x4*)((float*)Cout + (size_t)m * N + nb) = v;
            }
        }
    }
}

// ---------------- MFMA flash attention, XCD-local + reg-prefetch ------------
__global__ __launch_bounds__(256) void attn_mfma(const unsigned short* __restrict__ qkv,
                                                 unsigned short* __restrict__ out) {
    __shared__ __attribute__((aligned(16))) unsigned short Ks[64 * KSTR];
    __shared__ __attribute__((aligned(16))) unsigned short Vs[64 * KSTR];
    __shared__ __attribute__((aligned(16))) unsigned short Ps[64 * KSTR];

    const int tid = threadIdx.x;
    const int wid = tid >> 6;
    const int ln  = tid & 63;
    const int quad = ln >> 4;
    const int mr   = ln & 15;

    const int id = blockIdx.x;                 // 0..511
    const int local = id >> 3;                 // 0..63
    const int bh = (id & 7) * 4 + (local >> 4);
    const int pa = local & 15;
    const int b  = bh >> 4;
    const int nh = bh & 15;
    const size_t chan = (size_t)nh * 192;

    const int ksr = tid >> 2, ksc = tid & 3;
    const int vt0 = (tid & 31) * 2, vd0 = (tid >> 5) * 8;

    u16x8 kp0, kp1, vp0, vp1;   // prefetch registers

#pragma unroll
    for (int half = 0; half < 2; half++) {
        const int qt = half ? (31 - pa) : pa;
        const int qb = qt * 64;

        short8 qf0, qf1;
        {
            const int qrow = qb + wid * 16 + mr;
            const unsigned short* gq = qkv + ((size_t)(qrow * 2 + b)) * 3072 + chan + quad * 8;
            qf0 = *(const short8*)gq;
            qf1 = *(const short8*)(gq + 32);
        }

        const f32x4 zero = {0.f, 0.f, 0.f, 0.f};
        f32x4 o[4];
        float mo[4], lo[4];
#pragma unroll
        for (int d = 0; d < 4; d++) o[d] = zero;
#pragma unroll
        for (int r = 0; r < 4; r++) { mo[r] = -3.0e38f; lo[r] = 0.f; }

        {
            const unsigned short* gk = qkv + ((size_t)(ksr * 2 + b)) * 3072 + chan + 64 + ksc * 16;
            kp0 = *(const u16x8*)gk;
            kp1 = *(const u16x8*)(gk + 8);
            const unsigned short* gv = qkv + ((size_t)(vt0 * 2 + b)) * 3072 + chan + 128 + vd0;
            vp0 = *(const u16x8*)gv;
            vp1 = *(const u16x8*)(gv + 6144);
        }

        for (int kt = 0; kt <= qt; kt++) {
            __syncthreads();
            *(u16x8*)(Ks + ksr * KSTR + ksc * 16) = kp0;
            *(u16x8*)(Ks + ksr * KSTR + ksc * 16 + 8) = kp1;
#pragma unroll
            for (int j = 0; j < 8; j++) {
                u16x2 pr; pr.x = vp0[j]; pr.y = vp1[j];
                *(u16x2*)(Vs + (vd0 + j) * KSTR + vt0) = pr;
            }
            if (kt < qt) {
                const int nb = (kt + 1) * 64;
                const unsigned short* gk =
                    qkv + ((size_t)((nb + ksr) * 2 + b)) * 3072 + chan + 64 + ksc * 16;
                kp0 = *(const u16x8*)gk;
                kp1 = *(const u16x8*)(gk + 8);
                const unsigned short* gv =
                    qkv + ((size_t)((nb + vt0) * 2 + b)) * 3072 + chan + 128 + vd0;
                vp0 = *(const u16x8*)gv;
                vp1 = *(const u16x8*)(gv + 6144);
            }
            __syncthreads();

            f32x4 sacc[4];
#pragma unroll
            for (int n = 0; n < 4; n++) {
                sacc[n] = zero;
                const unsigned short* kb = Ks + (n * 16 + mr) * KSTR + quad * 8;
                short8 kfr0 = *(const short8*)kb;
                short8 kfr1 = *(const short8*)(kb + 32);
                sacc[n] = __builtin_amdgcn_mfma_f32_16x16x32_bf16(qf0, kfr0, sacc[n], 0, 0, 0);
                sacc[n] = __builtin_amdgcn_mfma_f32_16x16x32_bf16(qf1, kfr1, sacc[n], 0, 0, 0);
            }
            if (kt == qt) {
#pragma unroll
                for (int n = 0; n < 4; n++)
#pragma unroll
                    for (int r = 0; r < 4; r++)
                        if (n * 16 + mr > wid * 16 + quad * 4 + r) sacc[n][r] = -3.0e38f;
            }

#pragma unroll
            for (int r = 0; r < 4; r++) {
                float rm = fmaxf(fmaxf(sacc[0][r], sacc[1][r]), fmaxf(sacc[2][r], sacc[3][r]));
                rm = fmaxf(rm, __shfl_xor(rm, 1));
                rm = fmaxf(rm, __shfl_xor(rm, 2));
                rm = fmaxf(rm, __shfl_xor(rm, 4));
                rm = fmaxf(rm, __shfl_xor(rm, 8));
                const float mn = fmaxf(mo[r], rm);
                const float al = exp2f((mo[r] - mn) * SCL);
                mo[r] = mn;
                const float off = -mn * SCL;
                float ps = 0.f;
                unsigned short* prow = Ps + (wid * 16 + quad * 4 + r) * KSTR + mr;
#pragma unroll
                for (int n = 0; n < 4; n++) {
                    const float p = exp2f(fmaf(sacc[n][r], SCL, off));
                    const unsigned short pb = (unsigned short)(__float_as_uint(p) >> 16);
                    prow[n * 16] = pb;
                    ps += bf2f(pb);
                }
                lo[r] = lo[r] * al + ps;
#pragma unroll
                for (int d = 0; d < 4; d++) o[d][r] *= al;
            }

            {
                const unsigned short* pb = Ps + (wid * 16 + mr) * KSTR + quad * 8;
                short8 pa0 = *(const short8*)pb;
                short8 pa1 = *(const short8*)(pb + 32);
#pragma unroll
                for (int d = 0; d < 4; d++) {
                    const unsigned short* vb = Vs + (d * 16 + mr) * KSTR + quad * 8;
                    short8 vf0 = *(const short8*)vb;
                    short8 vf1 = *(const short8*)(vb + 32);
                    o[d] = __builtin_amdgcn_mfma_f32_16x16x32_bf16(pa0, vf0, o[d], 0, 0, 0);
                    o[d] = __builtin_amdgcn_mfma_f32_16x16x32_bf16(pa1, vf1, o[d], 0, 0, 0);
                }
            }
        }

#pragma unroll
        for (int r = 0; r < 4; r++) {
            float ls = lo[r];
            ls += __shfl_xor(ls, 1);
            ls += __shfl_xor(ls, 2);
            ls += __shfl_xor(ls, 4);
            ls += __shfl_xor(ls, 8);
            const float inv = 1.0f / ls;
            const int qrow = qb + wid * 16 + quad * 4 + r;
            unsigned short* po = out + ((size_t)(qrow * 2 + b)) * H_DIM + nh * HDIM + mr;
#pragma unroll
            for (int d = 0; d < 4; d++) po[d * 16] = f2bf(o[d][r] * inv);
        }
    }
}

extern "C" void kernel_launch(void* const* d_in, const int* in_sizes, int n_in,
                              void* d_out, int out_size, void* d_ws, size_t ws_size,
                              hipStream_t stream) {
    const float* x      = (const float*)d_in[0];
    const float* ln1_w  = (const float*)d_in[1];
    const float* ln1_b  = (const float*)d_in[2];
    const float* w_qkv  = (const float*)d_in[3];
    const float* b_qkv  = (const float*)d_in[4];
    const float* w_proj = (const float*)d_in[5];
    const float* b_proj = (const float*)d_in[6];
    const float* ln2_w  = (const float*)d_in[7];
    const float* ln2_b  = (const float*)d_in[8];
    const float* w_fc1  = (const float*)d_in[9];
    const float* b_fc1  = (const float*)d_in[10];
    const float* w_fc2  = (const float*)d_in[11];
    const float* b_fc2  = (const float*)d_in[12];
    float* out = (float*)d_out;

    char* ws = (char*)d_ws;
    unsigned short* wqkv_bf  = (unsigned short*)(ws);                        // 6 MB
    unsigned short* wproj_bf = (unsigned short*)(ws + ((size_t)6 << 20));    // 2 MB
    unsigned short* wfc1_bf  = (unsigned short*)(ws + ((size_t)8 << 20));    // 8 MB
    unsigned short* wfc2_bf  = (unsigned short*)(ws + ((size_t)16 << 20));   // 8 MB
    unsigned short* ln_buf   = (unsigned short*)(ws + ((size_t)24 << 20));   // 8 MB
    unsigned short* qkv_bf   = (unsigned short*)(ws + ((size_t)32 << 20));   // 24 MB
    unsigned short* attn_bf  = (unsigned short*)(ws + ((size_t)56 << 20));   // 8 MB
    unsigned short* fc1_bf   = (unsigned short*)(ws + ((size_t)32 << 20));   // 32 MB (qkv/attn dead)

    // fused weight cast: one launch, 12 M f32x4 elems
    cast_all<<<12288, 256, 0, stream>>>(w_qkv, w_proj, w_fc1, w_fc2,
                                        wqkv_bf, wproj_bf, wfc1_bf, wfc2_bf);

    // 1) LN1 -> bf16
    ln_bf16<<<M_ROWS, 256, 0, stream>>>(x, ln1_w, ln1_b, ln_buf);
    // 2) qkv = ln1 @ w_qkv^T + b_qkv   [4096,3072] bf16   (768 blocks)
    gemm_mfma<0, true, 128><<<768, 256, 0, stream>>>(
        ln_buf, wqkv_bf, b_qkv, nullptr, qkv_bf, M_ROWS, 3072, 1024);
    // 3) MFMA flash attention -> bf16 [4096,1024]   (512 blocks, XCD-local)
    attn_mfma<<<512, 256, 0, stream>>>(qkv_bf, attn_bf);
    // 4) x1 = x + attn @ w_proj^T + b_proj  -> d_out (fp32)   (512 blocks, TN=64)
    gemm_mfma<1, false, 64><<<512, 256, 0, stream>>>(
        attn_bf, wproj_bf, b_proj, x, out, M_ROWS, 1024, 1024);
    // 5) LN2 -> bf16
    ln_bf16<<<M_ROWS, 256, 0, stream>>>(out, ln2_w, ln2_b, ln_buf);
    // 6) fc1 + gelu -> bf16 [4096,4096]   (1024 blocks)
    gemm_mfma<2, true, 128><<<1024, 256, 0, stream>>>(
        ln_buf, wfc1_bf, b_fc1, nullptr, fc1_bf, M_ROWS, 4096, 1024);
    // 7) out = x1 + fc1 @ w_fc2^T + b_fc2 (in-place residual)   (512 blocks, TN=64)
    gemm_mfma<1, false, 64><<<512, 256, 0, stream>>>(
        fc1_bf, wfc2_bf, b_fc2, out, out, M_ROWS, 1024, 4096);
}

// Round 8
// 375.007 us; speedup vs baseline: 1.1134x; 1.0541x over previous
//
#include <hip/hip_runtime.h>
#include <math.h>

#define S_LEN 2048
#define B_SZ 2
#define NHEAD 16
#define HDIM 64
#define H_DIM 1024
#define M_ROWS (S_LEN * B_SZ)   // 4096
#define LN_EPS 1e-5f
#define KSTR 72                  // attn LDS row stride (shorts): 2-way banks = free
#define SCL 0.18033688011112042f // 0.125 * log2(e)

typedef __attribute__((ext_vector_type(4))) float f32x4;
typedef __attribute__((ext_vector_type(8))) short short8;
typedef __attribute__((ext_vector_type(8))) unsigned short u16x8;
typedef __attribute__((ext_vector_type(4))) unsigned short u16x4;
typedef __attribute__((ext_vector_type(2))) unsigned short u16x2;

__device__ __forceinline__ float bf2f(unsigned short u) {
    return __uint_as_float(((unsigned int)u) << 16);
}
__device__ __forceinline__ unsigned short f2bf(float f) {
    unsigned int u = __float_as_uint(f);
    return (unsigned short)((u + 0x7fffu + ((u >> 16) & 1u)) >> 16);
}
__device__ __forceinline__ void gld_lds16(const void* g, void* l) {
    __builtin_amdgcn_global_load_lds(
        (const __attribute__((address_space(1))) void*)g,
        (__attribute__((address_space(3))) void*)l, 16, 0, 0);
}

// ---------------- fused weight cast fp32 -> bf16 (single launch) ------------
__global__ __launch_bounds__(256) void cast_all(const float* __restrict__ wqkv,
                                                const float* __restrict__ wproj,
                                                const float* __restrict__ wfc1,
                                                const float* __restrict__ wfc2,
                                                unsigned short* __restrict__ oqkv,
                                                unsigned short* __restrict__ oproj,
                                                unsigned short* __restrict__ ofc1,
                                                unsigned short* __restrict__ ofc2) {
    const int i = blockIdx.x * 256 + threadIdx.x;   // grid covers 3145728
    const float* src; unsigned short* dst; int off;
    if (i < 786432)       { src = wqkv;  dst = oqkv;  off = i; }
    else if (i < 1048576) { src = wproj; dst = oproj; off = i - 786432; }
    else if (i < 2097152) { src = wfc1;  dst = ofc1;  off = i - 1048576; }
    else                  { src = wfc2;  dst = ofc2;  off = i - 2097152; }
    f32x4 v = ((const f32x4*)src)[off];
    u16x4 o;
    o.x = f2bf(v.x); o.y = f2bf(v.y); o.z = f2bf(v.z); o.w = f2bf(v.w);
    ((u16x4*)dst)[off] = o;
}

// ---------------- LayerNorm row of 1024 -> bf16 -----------------------------
__global__ __launch_bounds__(256) void ln_bf16(const float* __restrict__ x,
                                               const float* __restrict__ w,
                                               const float* __restrict__ b,
                                               unsigned short* __restrict__ y) {
    const int m = blockIdx.x;
    const int tid = threadIdx.x;
    const float* row = x + (size_t)m * H_DIM;

    float4 v = ((const float4*)row)[tid];
    float s  = v.x + v.y + v.z + v.w;
    float ss = v.x * v.x + v.y * v.y + v.z * v.z + v.w * v.w;

    __shared__ float rs[4], rss[4], stats[2];
    const int wave = tid >> 6, lane = tid & 63;
    for (int off = 32; off; off >>= 1) {
        s  += __shfl_down(s, off);
        ss += __shfl_down(ss, off);
    }
    if (lane == 0) { rs[wave] = s; rss[wave] = ss; }
    __syncthreads();
    if (tid == 0) {
        float S = rs[0] + rs[1] + rs[2] + rs[3];
        float SS = rss[0] + rss[1] + rss[2] + rss[3];
        float mean = S * (1.0f / H_DIM);
        float var = SS * (1.0f / H_DIM) - mean * mean;
        stats[0] = mean;
        stats[1] = rsqrtf(var + LN_EPS);
    }
    __syncthreads();
    const float mean = stats[0], inv = stats[1];
    float4 wv = ((const float4*)w)[tid];
    float4 bv = ((const float4*)b)[tid];
    u16x4 o;
    o.x = f2bf((v.x - mean) * inv * wv.x + bv.x);
    o.y = f2bf((v.y - mean) * inv * wv.y + bv.y);
    o.z = f2bf((v.z - mean) * inv * wv.z + bv.z);
    o.w = f2bf((v.w - mean) * inv * wv.w + bv.w);
    ((u16x4*)(y + (size_t)m * H_DIM))[tid] = o;
}

// ---------------- bf16 MFMA GEMM, dbuf + XCD swizzle + coalesced epi --------
template <int EPI, bool BF_OUT, int TN>
__global__ __launch_bounds__(256) void gemm_mfma(const unsigned short* __restrict__ A,
                                                 const unsigned short* __restrict__ B,
                                                 const float* __restrict__ bias,
                                                 const float* __restrict__ resid,
                                                 void* __restrict__ Cout,
                                                 int M, int N, int K) {
    constexpr int NJ = TN / 32;   // n-frags per wave
    __shared__ __attribute__((aligned(16))) unsigned short As[2][128 * 32];
    __shared__ __attribute__((aligned(16))) unsigned short Bs[2][TN * 32];

    const int tid = threadIdx.x;
    const int wid = tid >> 6;
    const int ln  = tid & 63;
    const int quad = ln >> 4;
    const int mr   = ln & 15;
    const int wm = (wid >> 1) * 64;
    const int wn = (wid & 1) * (TN / 2);

    const int mb = M >> 7;
    const int stripe = mb >> 3;               // 4 for M=4096
    const int xcd = blockIdx.x & 7;
    const int local = blockIdx.x >> 3;
    const int m0 = (xcd * stripe + (local % stripe)) << 7;
    const int n0 = (local / stripe) * TN;

    const int c  = wid * 64 + ln;
    const int r0 = c >> 2;
    const int k0 = (c & 3) * 8;
    const unsigned short* gA0 = A + (size_t)(m0 + r0) * K + k0;
    const unsigned short* gA1 = A + (size_t)(m0 + 64 + r0) * K + k0;
    const unsigned short* gB0 = B + (size_t)(n0 + r0) * K + k0;
    const unsigned short* gB1 = B + (size_t)(n0 + 64 + r0) * K + k0;  // TN=128 only
    const int lo0 = wid * 512;
    const int lo1 = 2048 + wid * 512;

    const f32x4 zero = {0.f, 0.f, 0.f, 0.f};
    f32x4 acc[4][NJ];
#pragma unroll
    for (int i = 0; i < 4; i++)
#pragma unroll
        for (int j = 0; j < NJ; j++) acc[i][j] = zero;

    const int nt = K >> 5;
    gld_lds16(gA0, As[0] + lo0);
    gld_lds16(gA1, As[0] + lo1);
    gld_lds16(gB0, Bs[0] + lo0);
    if constexpr (TN == 128) gld_lds16(gB1, Bs[0] + lo1);

    for (int kt = 0; kt < nt; kt++) {
        __syncthreads();
        const int nxt = kt + 1;
        if (nxt < nt) {
            const int nb_ = nxt & 1;
            const int koff = nxt * 32;
            gld_lds16(gA0 + koff, As[nb_] + lo0);
            gld_lds16(gA1 + koff, As[nb_] + lo1);
            gld_lds16(gB0 + koff, Bs[nb_] + lo0);
            if constexpr (TN == 128) gld_lds16(gB1 + koff, Bs[nb_] + lo1);
        }
        const unsigned short* as = As[kt & 1];
        const unsigned short* bs = Bs[kt & 1];
        short8 af[4], bfr[NJ];
#pragma unroll
        for (int i = 0; i < 4; i++)
            af[i] = *(const short8*)(as + (wm + i * 16 + mr) * 32 + quad * 8);
#pragma unroll
        for (int j = 0; j < NJ; j++)
            bfr[j] = *(const short8*)(bs + (wn + j * 16 + mr) * 32 + quad * 8);
#pragma unroll
        for (int i = 0; i < 4; i++)
#pragma unroll
            for (int j = 0; j < NJ; j++)
                acc[i][j] = __builtin_amdgcn_mfma_f32_16x16x32_bf16(bfr[j], af[i], acc[i][j], 0, 0, 0);
    }

    f32x4 bias4[NJ];
#pragma unroll
    for (int j = 0; j < NJ; j++)
        bias4[j] = *(const f32x4*)(bias + n0 + wn + j * 16 + quad * 4);

#pragma unroll
    for (int i = 0; i < 4; i++) {
        const int m = m0 + wm + i * 16 + mr;
#pragma unroll
        for (int j = 0; j < NJ; j++) {
            const int nb = n0 + wn + j * 16 + quad * 4;
            f32x4 v = acc[i][j] + bias4[j];
            if (EPI == 1) v += *(const f32x4*)(resid + (size_t)m * N + nb);
            if (EPI == 2) {
#pragma unroll
                for (int r = 0; r < 4; r++) {
                    const float t = v[r];
                    v[r] = 0.5f * t * (1.0f + tanhf(0.7978845608f * (t + 0.044715f * t * t * t)));
                }
            }
            if (BF_OUT) {
                u16x4 pk;
                pk.x = f2bf(v.x); pk.y = f2bf(v.y); pk.z = f2bf(v.z); pk.w = f2bf(v.w);
                *(u16x4*)((unsigned short*)Cout + (size_t)m * N + nb) = pk;
            } else {
                *(f32x4*)((float*)Cout + (size_t)m * N + nb) = v;
            }
        }
    }
}

// ---------------- MFMA flash attention v3 -----------------------------------
// XCD-local (K/V in XCD L2), reg-prefetch staging, max-free softmax.
// S^T trick: mfma(kfr, qf) -> lane owns q=mr, t=n*16+quad*4+r (vector P store).
// O^T trick: mfma(vf, pa)  -> lane owns q=mr, d=dblk*16+quad*4+r (vector O store,
// denominator needs no shuffle redistribution).
__global__ __launch_bounds__(256) void attn_mfma(const unsigned short* __restrict__ qkv,
                                                 unsigned short* __restrict__ out) {
    __shared__ __attribute__((aligned(16))) unsigned short Ks[64 * KSTR];
    __shared__ __attribute__((aligned(16))) unsigned short Vs[64 * KSTR];
    __shared__ __attribute__((aligned(16))) unsigned short Ps[64 * KSTR];

    const int tid = threadIdx.x;
    const int wid = tid >> 6;
    const int ln  = tid & 63;
    const int quad = ln >> 4;
    const int mr   = ln & 15;

    const int id = blockIdx.x;                 // 0..511
    const int local = id >> 3;                 // 0..63
    const int bh = (id & 7) * 4 + (local >> 4);
    const int pa = local & 15;
    const int b  = bh >> 4;
    const int nh = bh & 15;
    const size_t chan = (size_t)nh * 192;

    const int ksr = tid >> 2, ksc = tid & 3;
    const int vt0 = (tid & 31) * 2, vd0 = (tid >> 5) * 8;

    u16x8 kp0, kp1, vp0, vp1;   // prefetch registers

#pragma unroll
    for (int half = 0; half < 2; half++) {
        const int qt = half ? (31 - pa) : pa;
        const int qb = qt * 64;

        short8 qf0, qf1;
        {
            const int qrow = qb + wid * 16 + mr;
            const unsigned short* gq = qkv + ((size_t)(qrow * 2 + b)) * 3072 + chan + quad * 8;
            qf0 = *(const short8*)gq;
            qf1 = *(const short8*)(gq + 32);
        }

        const f32x4 zero = {0.f, 0.f, 0.f, 0.f};
        f32x4 o[4];
        float ps = 0.f;
#pragma unroll
        for (int d = 0; d < 4; d++) o[d] = zero;

        {
            const unsigned short* gk = qkv + ((size_t)(ksr * 2 + b)) * 3072 + chan + 64 + ksc * 16;
            kp0 = *(const u16x8*)gk;
            kp1 = *(const u16x8*)(gk + 8);
            const unsigned short* gv = qkv + ((size_t)(vt0 * 2 + b)) * 3072 + chan + 128 + vd0;
            vp0 = *(const u16x8*)gv;
            vp1 = *(const u16x8*)(gv + 6144);
        }

        for (int kt = 0; kt <= qt; kt++) {
            __syncthreads();
            *(u16x8*)(Ks + ksr * KSTR + ksc * 16) = kp0;
            *(u16x8*)(Ks + ksr * KSTR + ksc * 16 + 8) = kp1;
#pragma unroll
            for (int j = 0; j < 8; j++) {
                u16x2 pr; pr.x = vp0[j]; pr.y = vp1[j];
                *(u16x2*)(Vs + (vd0 + j) * KSTR + vt0) = pr;
            }
            if (kt < qt) {
                const int nb = (kt + 1) * 64;
                const unsigned short* gk =
                    qkv + ((size_t)((nb + ksr) * 2 + b)) * 3072 + chan + 64 + ksc * 16;
                kp0 = *(const u16x8*)gk;
                kp1 = *(const u16x8*)(gk + 8);
                const unsigned short* gv =
                    qkv + ((size_t)((nb + vt0) * 2 + b)) * 3072 + chan + 128 + vd0;
                vp0 = *(const u16x8*)gv;
                vp1 = *(const u16x8*)(gv + 6144);
            }
            __syncthreads();

            // ---- S^T = K Q^T: lane owns q=mr, t = n*16 + quad*4 + r ----
            f32x4 sacc[4];
#pragma unroll
            for (int n = 0; n < 4; n++) {
                sacc[n] = zero;
                const unsigned short* kb = Ks + (n * 16 + mr) * KSTR + quad * 8;
                short8 kfr0 = *(const short8*)kb;
                short8 kfr1 = *(const short8*)(kb + 32);
                sacc[n] = __builtin_amdgcn_mfma_f32_16x16x32_bf16(kfr0, qf0, sacc[n], 0, 0, 0);
                sacc[n] = __builtin_amdgcn_mfma_f32_16x16x32_bf16(kfr1, qf1, sacc[n], 0, 0, 0);
            }
            if (kt == qt) {
#pragma unroll
                for (int n = 0; n < 4; n++)
#pragma unroll
                    for (int r = 0; r < 4; r++)
                        if (n * 16 + quad * 4 + r > wid * 16 + mr) sacc[n][r] = -3.0e38f;
            }

            // ---- max-free softmax: p = 2^(s*SCL), clamped; fp32 row-partials ----
            unsigned short* prow = Ps + (wid * 16 + mr) * KSTR + quad * 4;
#pragma unroll
            for (int n = 0; n < 4; n++) {
                u16x4 pk;
#pragma unroll
                for (int r = 0; r < 4; r++) {
                    const float p = exp2f(fminf(sacc[n][r] * SCL, 80.f));
                    ps += p;
                    pk[r] = (unsigned short)(__float_as_uint(p) >> 16);
                }
                *(u16x4*)(prow + n * 16) = pk;
            }

            // ---- O^T += V^T P^T: lane owns q=mr, d = dblk*16 + quad*4 + r ----
            {
                const unsigned short* pb = Ps + (wid * 16 + mr) * KSTR + quad * 8;
                short8 pa0 = *(const short8*)pb;
                short8 pa1 = *(const short8*)(pb + 32);
#pragma unroll
                for (int d = 0; d < 4; d++) {
                    const unsigned short* vb = Vs + (d * 16 + mr) * KSTR + quad * 8;
                    short8 vf0 = *(const short8*)vb;
                    short8 vf1 = *(const short8*)(vb + 32);
                    o[d] = __builtin_amdgcn_mfma_f32_16x16x32_bf16(vf0, pa0, o[d], 0, 0, 0);
                    o[d] = __builtin_amdgcn_mfma_f32_16x16x32_bf16(vf1, pa1, o[d], 0, 0, 0);
                }
            }
        }

        // ---- epilogue: l[q=mr] via 2 shfl_xor; vectorized O store ----
        ps += __shfl_xor(ps, 16);
        ps += __shfl_xor(ps, 32);
        const float inv = 1.0f / ps;
        const int qrow = qb + wid * 16 + mr;
        unsigned short* po = out + ((size_t)(qrow * 2 + b)) * H_DIM + nh * HDIM;
#pragma unroll
        for (int d = 0; d < 4; d++) {
            u16x4 pk;
#pragma unroll
            for (int r = 0; r < 4; r++) pk[r] = f2bf(o[d][r] * inv);
            *(u16x4*)(po + d * 16 + quad * 4) = pk;
        }
    }
}

extern "C" void kernel_launch(void* const* d_in, const int* in_sizes, int n_in,
                              void* d_out, int out_size, void* d_ws, size_t ws_size,
                              hipStream_t stream) {
    const float* x      = (const float*)d_in[0];
    const float* ln1_w  = (const float*)d_in[1];
    const float* ln1_b  = (const float*)d_in[2];
    const float* w_qkv  = (const float*)d_in[3];
    const float* b_qkv  = (const float*)d_in[4];
    const float* w_proj = (const float*)d_in[5];
    const float* b_proj = (const float*)d_in[6];
    const float* ln2_w  = (const float*)d_in[7];
    const float* ln2_b  = (const float*)d_in[8];
    const float* w_fc1  = (const float*)d_in[9];
    const float* b_fc1  = (const float*)d_in[10];
    const float* w_fc2  = (const float*)d_in[11];
    const float* b_fc2  = (const float*)d_in[12];
    float* out = (float*)d_out;

    char* ws = (char*)d_ws;
    unsigned short* wqkv_bf  = (unsigned short*)(ws);                        // 6 MB
    unsigned short* wproj_bf = (unsigned short*)(ws + ((size_t)6 << 20));    // 2 MB
    unsigned short* wfc1_bf  = (unsigned short*)(ws + ((size_t)8 << 20));    // 8 MB
    unsigned short* wfc2_bf  = (unsigned short*)(ws + ((size_t)16 << 20));   // 8 MB
    unsigned short* ln_buf   = (unsigned short*)(ws + ((size_t)24 << 20));   // 8 MB
    unsigned short* qkv_bf   = (unsigned short*)(ws + ((size_t)32 << 20));   // 24 MB
    unsigned short* attn_bf  = (unsigned short*)(ws + ((size_t)56 << 20));   // 8 MB
    unsigned short* fc1_bf   = (unsigned short*)(ws + ((size_t)32 << 20));   // 32 MB (qkv/attn dead)

    cast_all<<<12288, 256, 0, stream>>>(w_qkv, w_proj, w_fc1, w_fc2,
                                        wqkv_bf, wproj_bf, wfc1_bf, wfc2_bf);

    // 1) LN1 -> bf16
    ln_bf16<<<M_ROWS, 256, 0, stream>>>(x, ln1_w, ln1_b, ln_buf);
    // 2) qkv = ln1 @ w_qkv^T + b_qkv   [4096,3072] bf16   (768 blocks)
    gemm_mfma<0, true, 128><<<768, 256, 0, stream>>>(
        ln_buf, wqkv_bf, b_qkv, nullptr, qkv_bf, M_ROWS, 3072, 1024);
    // 3) MFMA flash attention -> bf16 [4096,1024]   (512 blocks, XCD-local)
    attn_mfma<<<512, 256, 0, stream>>>(qkv_bf, attn_bf);
    // 4) x1 = x + attn @ w_proj^T + b_proj  -> d_out (fp32)   (512 blocks, TN=64)
    gemm_mfma<1, false, 64><<<512, 256, 0, stream>>>(
        attn_bf, wproj_bf, b_proj, x, out, M_ROWS, 1024, 1024);
    // 5) LN2 -> bf16
    ln_bf16<<<M_ROWS, 256, 0, stream>>>(out, ln2_w, ln2_b, ln_buf);
    // 6) fc1 + gelu -> bf16 [4096,4096]   (1024 blocks)
    gemm_mfma<2, true, 128><<<1024, 256, 0, stream>>>(
        ln_buf, wfc1_bf, b_fc1, nullptr, fc1_bf, M_ROWS, 4096, 1024);
    // 7) out = x1 + fc1 @ w_fc2^T + b_fc2 (in-place residual)   (512 blocks, TN=64)
    gemm_mfma<1, false, 64><<<512, 256, 0, stream>>>(
        fc1_bf, wfc2_bf, b_fc2, out, out, M_ROWS, 1024, 4096);
}

// Round 9
// 356.860 us; speedup vs baseline: 1.1700x; 1.0509x over previous
//
#include <hip/hip_runtime.h>
#include <math.h>

#define S_LEN 2048
#define B_SZ 2
#define NHEAD 16
#define HDIM 64
#define H_DIM 1024
#define M_ROWS (S_LEN * B_SZ)   // 4096
#define LN_EPS 1e-5f
#define KSTR 72                  // attn LDS row stride (shorts): 2-way banks = free
#define SCL 0.18033688011112042f // 0.125 * log2(e)

typedef __attribute__((ext_vector_type(4))) float f32x4;
typedef __attribute__((ext_vector_type(8))) short short8;
typedef __attribute__((ext_vector_type(8))) unsigned short u16x8;
typedef __attribute__((ext_vector_type(4))) unsigned short u16x4;
typedef __attribute__((ext_vector_type(2))) unsigned short u16x2;

__device__ __forceinline__ float bf2f(unsigned short u) {
    return __uint_as_float(((unsigned int)u) << 16);
}
__device__ __forceinline__ unsigned short f2bf(float f) {
    unsigned int u = __float_as_uint(f);
    return (unsigned short)((u + 0x7fffu + ((u >> 16) & 1u)) >> 16);
}

// ---------------- fused weight cast fp32 -> bf16 (single launch) ------------
__global__ __launch_bounds__(256) void cast_all(const float* __restrict__ wqkv,
                                                const float* __restrict__ wproj,
                                                const float* __restrict__ wfc1,
                                                const float* __restrict__ wfc2,
                                                unsigned short* __restrict__ oqkv,
                                                unsigned short* __restrict__ oproj,
                                                unsigned short* __restrict__ ofc1,
                                                unsigned short* __restrict__ ofc2) {
    const int i = blockIdx.x * 256 + threadIdx.x;   // grid covers 3145728
    const float* src; unsigned short* dst; int off;
    if (i < 786432)       { src = wqkv;  dst = oqkv;  off = i; }
    else if (i < 1048576) { src = wproj; dst = oproj; off = i - 786432; }
    else if (i < 2097152) { src = wfc1;  dst = ofc1;  off = i - 1048576; }
    else                  { src = wfc2;  dst = ofc2;  off = i - 2097152; }
    f32x4 v = ((const f32x4*)src)[off];
    u16x4 o;
    o.x = f2bf(v.x); o.y = f2bf(v.y); o.z = f2bf(v.z); o.w = f2bf(v.w);
    ((u16x4*)dst)[off] = o;
}

// ---------------- LayerNorm row of 1024 -> bf16 -----------------------------
__global__ __launch_bounds__(256) void ln_bf16(const float* __restrict__ x,
                                               const float* __restrict__ w,
                                               const float* __restrict__ b,
                                               unsigned short* __restrict__ y) {
    const int m = blockIdx.x;
    const int tid = threadIdx.x;
    const float* row = x + (size_t)m * H_DIM;

    float4 v = ((const float4*)row)[tid];
    float s  = v.x + v.y + v.z + v.w;
    float ss = v.x * v.x + v.y * v.y + v.z * v.z + v.w * v.w;

    __shared__ float rs[4], rss[4], stats[2];
    const int wave = tid >> 6, lane = tid & 63;
    for (int off = 32; off; off >>= 1) {
        s  += __shfl_down(s, off);
        ss += __shfl_down(ss, off);
    }
    if (lane == 0) { rs[wave] = s; rss[wave] = ss; }
    __syncthreads();
    if (tid == 0) {
        float S = rs[0] + rs[1] + rs[2] + rs[3];
        float SS = rss[0] + rss[1] + rss[2] + rss[3];
        float mean = S * (1.0f / H_DIM);
        float var = SS * (1.0f / H_DIM) - mean * mean;
        stats[0] = mean;
        stats[1] = rsqrtf(var + LN_EPS);
    }
    __syncthreads();
    const float mean = stats[0], inv = stats[1];
    float4 wv = ((const float4*)w)[tid];
    float4 bv = ((const float4*)b)[tid];
    u16x4 o;
    o.x = f2bf((v.x - mean) * inv * wv.x + bv.x);
    o.y = f2bf((v.y - mean) * inv * wv.y + bv.y);
    o.z = f2bf((v.z - mean) * inv * wv.z + bv.z);
    o.w = f2bf((v.w - mean) * inv * wv.w + bv.w);
    ((u16x4*)(y + (size_t)m * H_DIM))[tid] = o;
}

// ---------------- bf16 MFMA GEMM v2: reg-staged pipeline, BK=64 -------------
// C[M,N] = A[M,K] @ B[N,K]^T + bias. EPI: 0=bias, 1=+resid, 2=+gelu.
// Staging: global->VGPR loads issued one iteration ahead (NOT drained by
// s_barrier, unlike global_load_lds whose vmcnt(0) drain is the m97 stall),
// committed to single-buffer LDS (stride 72 shorts: 2-way banks = free)
// between two lgkm-only barriers. BK=64 halves barrier count.
template <int EPI, bool BF_OUT, int TN>
__global__ __launch_bounds__(256) void gemm_mfma(const unsigned short* __restrict__ A,
                                                 const unsigned short* __restrict__ B,
                                                 const float* __restrict__ bias,
                                                 const float* __restrict__ resid,
                                                 void* __restrict__ Cout,
                                                 int M, int N, int K) {
    constexpr int NJ = TN / 32;                // n-frags per wave
    constexpr int ST = 72;                     // LDS row stride (shorts)
    constexpr int BNR = (TN == 128) ? 4 : 2;   // B staging regs (u16x8)
    __shared__ __attribute__((aligned(16))) unsigned short As[128 * ST];
    __shared__ __attribute__((aligned(16))) unsigned short Bs[TN * ST];

    const int tid = threadIdx.x;
    const int wid = tid >> 6;
    const int ln  = tid & 63;
    const int quad = ln >> 4;
    const int mr   = ln & 15;
    const int wm = (wid >> 1) * 64;
    const int wn = (wid & 1) * (TN / 2);

    const int mb = M >> 7;
    const int stripe = mb >> 3;               // 4 for M=4096
    const int xcd = blockIdx.x & 7;
    const int local = blockIdx.x >> 3;
    const int m0 = (xcd * stripe + (local % stripe)) << 7;
    const int n0 = (local / stripe) * TN;

    // A staging: thread -> row tid>>1, k-span (tid&1)*32 .. +32 (4 u16x8)
    const int ar = tid >> 1, aks = (tid & 1) * 32;
    const unsigned short* gA = A + (size_t)(m0 + ar) * K + aks;
    unsigned short* lA = As + ar * ST + aks;
    // B staging: TN=128 like A; TN=64: row tid>>2, k-span (tid&3)*16 (2 u16x8)
    const int br  = (TN == 128) ? (tid >> 1) : (tid >> 2);
    const int bks = (TN == 128) ? ((tid & 1) * 32) : ((tid & 3) * 16);
    const unsigned short* gB = B + (size_t)(n0 + br) * K + bks;
    unsigned short* lB = Bs + br * ST + bks;

    u16x8 apf[4], bpf[BNR];
    auto load_tile = [&](int kt) {
        const unsigned short* pa = gA + kt * 64;
#pragma unroll
        for (int r = 0; r < 4; r++) apf[r] = *(const u16x8*)(pa + r * 8);
        const unsigned short* pb = gB + kt * 64;
#pragma unroll
        for (int r = 0; r < BNR; r++) bpf[r] = *(const u16x8*)(pb + r * 8);
    };
    auto store_tile = [&]() {
#pragma unroll
        for (int r = 0; r < 4; r++) *(u16x8*)(lA + r * 8) = apf[r];
#pragma unroll
        for (int r = 0; r < BNR; r++) *(u16x8*)(lB + r * 8) = bpf[r];
    };

    const f32x4 zero = {0.f, 0.f, 0.f, 0.f};
    f32x4 acc[4][NJ];
#pragma unroll
    for (int i = 0; i < 4; i++)
#pragma unroll
        for (int j = 0; j < NJ; j++) acc[i][j] = zero;

    const int nt = K >> 6;
    load_tile(0);
    store_tile();
    if (nt > 1) load_tile(1);
    __syncthreads();

    for (int kt = 0; kt < nt; kt++) {
#pragma unroll
        for (int h = 0; h < 2; h++) {
            short8 af[4], bf[NJ];
#pragma unroll
            for (int i = 0; i < 4; i++)
                af[i] = *(const short8*)(As + (wm + i * 16 + mr) * ST + h * 32 + quad * 8);
#pragma unroll
            for (int j = 0; j < NJ; j++)
                bf[j] = *(const short8*)(Bs + (wn + j * 16 + mr) * ST + h * 32 + quad * 8);
#pragma unroll
            for (int i = 0; i < 4; i++)
#pragma unroll
                for (int j = 0; j < NJ; j++)
                    acc[i][j] = __builtin_amdgcn_mfma_f32_16x16x32_bf16(bf[j], af[i], acc[i][j], 0, 0, 0);
        }
        if (kt + 1 < nt) {
            __syncthreads();           // all waves done reading tile kt
            store_tile();              // commit tile kt+1 (waits its loads here)
            if (kt + 2 < nt) load_tile(kt + 2);   // in flight across next iter
            __syncthreads();           // tile kt+1 visible
        }
    }

    // epilogue: per-lane 4 consecutive n at fixed m; j-inner stores merge lines
    f32x4 bias4[NJ];
#pragma unroll
    for (int j = 0; j < NJ; j++)
        bias4[j] = *(const f32x4*)(bias + n0 + wn + j * 16 + quad * 4);

#pragma unroll
    for (int i = 0; i < 4; i++) {
        const int m = m0 + wm + i * 16 + mr;
#pragma unroll
        for (int j = 0; j < NJ; j++) {
            const int nb = n0 + wn + j * 16 + quad * 4;
            f32x4 v = acc[i][j] + bias4[j];
            if (EPI == 1) v += *(const f32x4*)(resid + (size_t)m * N + nb);
            if (EPI == 2) {
#pragma unroll
                for (int r = 0; r < 4; r++) {
                    const float t = v[r];
                    v[r] = 0.5f * t * (1.0f + tanhf(0.7978845608f * (t + 0.044715f * t * t * t)));
                }
            }
            if (BF_OUT) {
                u16x4 pk;
                pk.x = f2bf(v.x); pk.y = f2bf(v.y); pk.z = f2bf(v.z); pk.w = f2bf(v.w);
                *(u16x4*)((unsigned short*)Cout + (size_t)m * N + nb) = pk;
            } else {
                *(f32x4*)((float*)Cout + (size_t)m * N + nb) = v;
            }
        }
    }
}

// ---------------- MFMA flash attention v3 -----------------------------------
// XCD-local (K/V in XCD L2), reg-prefetch staging, max-free softmax.
__global__ __launch_bounds__(256) void attn_mfma(const unsigned short* __restrict__ qkv,
                                                 unsigned short* __restrict__ out) {
    __shared__ __attribute__((aligned(16))) unsigned short Ks[64 * KSTR];
    __shared__ __attribute__((aligned(16))) unsigned short Vs[64 * KSTR];
    __shared__ __attribute__((aligned(16))) unsigned short Ps[64 * KSTR];

    const int tid = threadIdx.x;
    const int wid = tid >> 6;
    const int ln  = tid & 63;
    const int quad = ln >> 4;
    const int mr   = ln & 15;

    const int id = blockIdx.x;                 // 0..511
    const int local = id >> 3;                 // 0..63
    const int bh = (id & 7) * 4 + (local >> 4);
    const int pa = local & 15;
    const int b  = bh >> 4;
    const int nh = bh & 15;
    const size_t chan = (size_t)nh * 192;

    const int ksr = tid >> 2, ksc = tid & 3;
    const int vt0 = (tid & 31) * 2, vd0 = (tid >> 5) * 8;

    u16x8 kp0, kp1, vp0, vp1;   // prefetch registers

#pragma unroll
    for (int half = 0; half < 2; half++) {
        const int qt = half ? (31 - pa) : pa;
        const int qb = qt * 64;

        short8 qf0, qf1;
        {
            const int qrow = qb + wid * 16 + mr;
            const unsigned short* gq = qkv + ((size_t)(qrow * 2 + b)) * 3072 + chan + quad * 8;
            qf0 = *(const short8*)gq;
            qf1 = *(const short8*)(gq + 32);
        }

        const f32x4 zero = {0.f, 0.f, 0.f, 0.f};
        f32x4 o[4];
        float ps = 0.f;
#pragma unroll
        for (int d = 0; d < 4; d++) o[d] = zero;

        {
            const unsigned short* gk = qkv + ((size_t)(ksr * 2 + b)) * 3072 + chan + 64 + ksc * 16;
            kp0 = *(const u16x8*)gk;
            kp1 = *(const u16x8*)(gk + 8);
            const unsigned short* gv = qkv + ((size_t)(vt0 * 2 + b)) * 3072 + chan + 128 + vd0;
            vp0 = *(const u16x8*)gv;
            vp1 = *(const u16x8*)(gv + 6144);
        }

        for (int kt = 0; kt <= qt; kt++) {
            __syncthreads();
            *(u16x8*)(Ks + ksr * KSTR + ksc * 16) = kp0;
            *(u16x8*)(Ks + ksr * KSTR + ksc * 16 + 8) = kp1;
#pragma unroll
            for (int j = 0; j < 8; j++) {
                u16x2 pr; pr.x = vp0[j]; pr.y = vp1[j];
                *(u16x2*)(Vs + (vd0 + j) * KSTR + vt0) = pr;
            }
            if (kt < qt) {
                const int nb = (kt + 1) * 64;
                const unsigned short* gk =
                    qkv + ((size_t)((nb + ksr) * 2 + b)) * 3072 + chan + 64 + ksc * 16;
                kp0 = *(const u16x8*)gk;
                kp1 = *(const u16x8*)(gk + 8);
                const unsigned short* gv =
                    qkv + ((size_t)((nb + vt0) * 2 + b)) * 3072 + chan + 128 + vd0;
                vp0 = *(const u16x8*)gv;
                vp1 = *(const u16x8*)(gv + 6144);
            }
            __syncthreads();

            // ---- S^T = K Q^T: lane owns q=mr, t = n*16 + quad*4 + r ----
            f32x4 sacc[4];
#pragma unroll
            for (int n = 0; n < 4; n++) {
                sacc[n] = zero;
                const unsigned short* kb = Ks + (n * 16 + mr) * KSTR + quad * 8;
                short8 kfr0 = *(const short8*)kb;
                short8 kfr1 = *(const short8*)(kb + 32);
                sacc[n] = __builtin_amdgcn_mfma_f32_16x16x32_bf16(kfr0, qf0, sacc[n], 0, 0, 0);
                sacc[n] = __builtin_amdgcn_mfma_f32_16x16x32_bf16(kfr1, qf1, sacc[n], 0, 0, 0);
            }
            if (kt == qt) {
#pragma unroll
                for (int n = 0; n < 4; n++)
#pragma unroll
                    for (int r = 0; r < 4; r++)
                        if (n * 16 + quad * 4 + r > wid * 16 + mr) sacc[n][r] = -3.0e38f;
            }

            // ---- max-free softmax: p = 2^(s*SCL), clamped; fp32 row-partials ----
            unsigned short* prow = Ps + (wid * 16 + mr) * KSTR + quad * 4;
#pragma unroll
            for (int n = 0; n < 4; n++) {
                u16x4 pk;
#pragma unroll
                for (int r = 0; r < 4; r++) {
                    const float p = exp2f(fminf(sacc[n][r] * SCL, 80.f));
                    ps += p;
                    pk[r] = (unsigned short)(__float_as_uint(p) >> 16);
                }
                *(u16x4*)(prow + n * 16) = pk;
            }

            // ---- O^T += V^T P^T: lane owns q=mr, d = dblk*16 + quad*4 + r ----
            {
                const unsigned short* pb = Ps + (wid * 16 + mr) * KSTR + quad * 8;
                short8 pa0 = *(const short8*)pb;
                short8 pa1 = *(const short8*)(pb + 32);
#pragma unroll
                for (int d = 0; d < 4; d++) {
                    const unsigned short* vb = Vs + (d * 16 + mr) * KSTR + quad * 8;
                    short8 vf0 = *(const short8*)vb;
                    short8 vf1 = *(const short8*)(vb + 32);
                    o[d] = __builtin_amdgcn_mfma_f32_16x16x32_bf16(vf0, pa0, o[d], 0, 0, 0);
                    o[d] = __builtin_amdgcn_mfma_f32_16x16x32_bf16(vf1, pa1, o[d], 0, 0, 0);
                }
            }
        }

        // ---- epilogue: l[q=mr] via 2 shfl_xor; vectorized O store ----
        ps += __shfl_xor(ps, 16);
        ps += __shfl_xor(ps, 32);
        const float inv = 1.0f / ps;
        const int qrow = qb + wid * 16 + mr;
        unsigned short* po = out + ((size_t)(qrow * 2 + b)) * H_DIM + nh * HDIM;
#pragma unroll
        for (int d = 0; d < 4; d++) {
            u16x4 pk;
#pragma unroll
            for (int r = 0; r < 4; r++) pk[r] = f2bf(o[d][r] * inv);
            *(u16x4*)(po + d * 16 + quad * 4) = pk;
        }
    }
}

extern "C" void kernel_launch(void* const* d_in, const int* in_sizes, int n_in,
                              void* d_out, int out_size, void* d_ws, size_t ws_size,
                              hipStream_t stream) {
    const float* x      = (const float*)d_in[0];
    const float* ln1_w  = (const float*)d_in[1];
    const float* ln1_b  = (const float*)d_in[2];
    const float* w_qkv  = (const float*)d_in[3];
    const float* b_qkv  = (const float*)d_in[4];
    const float* w_proj = (const float*)d_in[5];
    const float* b_proj = (const float*)d_in[6];
    const float* ln2_w  = (const float*)d_in[7];
    const float* ln2_b  = (const float*)d_in[8];
    const float* w_fc1  = (const float*)d_in[9];
    const float* b_fc1  = (const float*)d_in[10];
    const float* w_fc2  = (const float*)d_in[11];
    const float* b_fc2  = (const float*)d_in[12];
    float* out = (float*)d_out;

    char* ws = (char*)d_ws;
    unsigned short* wqkv_bf  = (unsigned short*)(ws);                        // 6 MB
    unsigned short* wproj_bf = (unsigned short*)(ws + ((size_t)6 << 20));    // 2 MB
    unsigned short* wfc1_bf  = (unsigned short*)(ws + ((size_t)8 << 20));    // 8 MB
    unsigned short* wfc2_bf  = (unsigned short*)(ws + ((size_t)16 << 20));   // 8 MB
    unsigned short* ln_buf   = (unsigned short*)(ws + ((size_t)24 << 20));   // 8 MB
    unsigned short* qkv_bf   = (unsigned short*)(ws + ((size_t)32 << 20));   // 24 MB
    unsigned short* attn_bf  = (unsigned short*)(ws + ((size_t)56 << 20));   // 8 MB
    unsigned short* fc1_bf   = (unsigned short*)(ws + ((size_t)32 << 20));   // 32 MB (qkv/attn dead)

    cast_all<<<12288, 256, 0, stream>>>(w_qkv, w_proj, w_fc1, w_fc2,
                                        wqkv_bf, wproj_bf, wfc1_bf, wfc2_bf);

    // 1) LN1 -> bf16
    ln_bf16<<<M_ROWS, 256, 0, stream>>>(x, ln1_w, ln1_b, ln_buf);
    // 2) qkv = ln1 @ w_qkv^T + b_qkv   [4096,3072] bf16   (768 blocks)
    gemm_mfma<0, true, 128><<<768, 256, 0, stream>>>(
        ln_buf, wqkv_bf, b_qkv, nullptr, qkv_bf, M_ROWS, 3072, 1024);
    // 3) MFMA flash attention -> bf16 [4096,1024]   (512 blocks, XCD-local)
    attn_mfma<<<512, 256, 0, stream>>>(qkv_bf, attn_bf);
    // 4) x1 = x + attn @ w_proj^T + b_proj  -> d_out (fp32)   (512 blocks, TN=64)
    gemm_mfma<1, false, 64><<<512, 256, 0, stream>>>(
        attn_bf, wproj_bf, b_proj, x, out, M_ROWS, 1024, 1024);
    // 5) LN2 -> bf16
    ln_bf16<<<M_ROWS, 256, 0, stream>>>(out, ln2_w, ln2_b, ln_buf);
    // 6) fc1 + gelu -> bf16 [4096,4096]   (1024 blocks)
    gemm_mfma<2, true, 128><<<1024, 256, 0, stream>>>(
        ln_buf, wfc1_bf, b_fc1, nullptr, fc1_bf, M_ROWS, 4096, 1024);
    // 7) out = x1 + fc1 @ w_fc2^T + b_fc2 (in-place residual)   (512 blocks, TN=64)
    gemm_mfma<1, false, 64><<<512, 256, 0, stream>>>(
        fc1_bf, wfc2_bf, b_fc2, out, out, M_ROWS, 1024, 4096);
}